// Round 3
// baseline (19915.198 us; speedup 1.0000x reference)
//
#include <hip/hip_runtime.h>
#include <cstdint>

#define DEV __device__ __forceinline__

typedef unsigned short ushort8 __attribute__((ext_vector_type(8)));
typedef unsigned int uint32;

#if __has_builtin(__builtin_amdgcn_rcpf)
DEV float rcp_fast(float x) { return __builtin_amdgcn_rcpf(x); }
#else
DEV float rcp_fast(float x) { return 1.f / x; }
#endif

// tanh(x) = 1 - 2/(exp(2x)+1): safe at +/-inf (no NaN), ~1e-7 rel err.
DEV float tanh_fast(float x) {
  float z = __expf(2.f * x);
  return 1.f - 2.f * rcp_fast(z + 1.f);
}
DEV float sigmoid_fast(float x) {
  return rcp_fast(1.f + __expf(-x));
}

// bf16 helpers (RTN pack; unpack via bit shift).
DEV unsigned short f2bf(float f) {
  uint32 u = __float_as_uint(f);
  u += 0x7FFFu + ((u >> 16) & 1u);
  return (unsigned short)(u >> 16);
}
DEV float bf2f(unsigned short s) { return __uint_as_float(((uint32)s) << 16); }
DEV float bf2f_lo(uint32 u) { return __uint_as_float(u << 16); }
DEV float bf2f_hi(uint32 u) { return __uint_as_float(u & 0xFFFF0000u); }

// ---------------- prep: decoder cell weights -> bf16 -----------------------
__global__ __launch_bounds__(256) void k_prep(const float* __restrict__ RHw,
                                              const float* __restrict__ RTw,
                                              unsigned short* __restrict__ out) {
  int i = blockIdx.x * 256 + threadIdx.x;
  if (i < 49152) {
    out[i] = f2bf(RHw[i]);
    out[49152 + i] = f2bf(RTw[i]);
  }
}

// ---------------- conv0: [B,T,16] -> [B,T,64], k=5 pad=2, +bias, ReLU ------
__global__ __launch_bounds__(256) void k_conv0(
    const float* __restrict__ x, const float* __restrict__ w,
    const float* __restrict__ bias, float* __restrict__ out) {
  __shared__ float wl[16 * 5 * 64];
  __shared__ float xl[68 * 16];
  const int blk = blockIdx.x;
  const int b = blk >> 2, tt = blk & 3;
  const int tid = threadIdx.x;
  for (int i = tid; i < 5120; i += 256) {
    int o = i / 80, rem = i % 80, ii = rem / 5, kk = rem % 5;
    wl[(ii * 5 + kk) * 64 + o] = w[i];
  }
  const int t0 = tt * 64;
  for (int i = tid; i < 68 * 16; i += 256) {
    int row = i >> 4, c = i & 15;
    int t = t0 - 2 + row;
    xl[i] = (t >= 0 && t < 256) ? x[((b << 8) + t) * 16 + c] : 0.f;
  }
  __syncthreads();
  const int o = tid & 63, tr = tid >> 6;
  for (int j = 0; j < 16; ++j) {
    int tl = tr * 16 + j;
    float acc = bias[o];
#pragma unroll
    for (int kk = 0; kk < 5; ++kk)
#pragma unroll
      for (int ii = 0; ii < 16; ++ii)
        acc += xl[(tl + kk) * 16 + ii] * wl[(ii * 5 + kk) * 64 + o];
    out[((b << 8) + t0 + tl) * 64 + o] = fmaxf(acc, 0.f);
  }
}

// ---------------- conv1: [B,T,64] -> [B,T,64], k=5 pad=2, +bias, ReLU ------
__global__ __launch_bounds__(256) void k_conv1(
    const float* __restrict__ in0, const float* __restrict__ w,
    const float* __restrict__ bias, float* __restrict__ out) {
  __shared__ float wl[64 * 5 * 64];  // 80 KB
  __shared__ float xl[68 * 64];      // 17 KB
  const int blk = blockIdx.x;
  const int b = blk >> 2, tt = blk & 3;
  const int tid = threadIdx.x;
  for (int i = tid; i < 64 * 5 * 64; i += 256) {
    int o = i / 320, rem = i % 320, ii = rem / 5, kk = rem % 5;
    wl[(ii * 5 + kk) * 64 + o] = w[i];
  }
  const int t0 = tt * 64;
  for (int i = tid; i < 68 * 64; i += 256) {
    int row = i >> 6, c = i & 63;
    int t = t0 - 2 + row;
    xl[i] = (t >= 0 && t < 256) ? in0[((b << 8) + t) * 64 + c] : 0.f;
  }
  __syncthreads();
  const int o = tid & 63, tr = tid >> 6;
  for (int j = 0; j < 16; ++j) {
    int tl = tr * 16 + j;
    float acc = bias[o];
    for (int kk = 0; kk < 5; ++kk) {
#pragma unroll 16
      for (int ii = 0; ii < 64; ++ii)
        acc += xl[(tl + kk) * 64 + ii] * wl[(ii * 5 + kk) * 64 + o];
    }
    out[((b << 8) + t0 + tl) * 64 + o] = fmaxf(acc, 0.f);
  }
}

// --------- c2e (+bias) fused with encoder input projections x@WH, x@WT -----
__global__ __launch_bounds__(256) void k_c2e_proj(
    const float* __restrict__ in1, const float* __restrict__ cw,
    const float* __restrict__ cb, const float* __restrict__ WH,
    const float* __restrict__ WT, float* __restrict__ xph,
    float* __restrict__ xpt) {
  __shared__ float xin[64 * 64];
  __shared__ float w1[64 * 64];
  __shared__ float xe[64 * 64];
  __shared__ float wh[64 * 128];
  __shared__ float wt[64 * 128];
  const int blk = blockIdx.x;
  const int b = blk >> 2, tt = blk & 3;
  const int tid = threadIdx.x;
  for (int i = tid; i < 4096; i += 256) {
    xin[i] = in1[(size_t)(((b << 8) + tt * 64)) * 64 + i];
    w1[i] = cw[i];
  }
  for (int i = tid; i < 8192; i += 256) {
    wh[i] = WH[i];
    wt[i] = WT[i];
  }
  __syncthreads();
  {
    const int o = tid & 63, tr = tid >> 6;
    for (int j = 0; j < 16; ++j) {
      int tl = tr * 16 + j;
      float acc = cb[o];
#pragma unroll 16
      for (int k = 0; k < 64; ++k) acc += xin[tl * 64 + k] * w1[k * 64 + o];
      xe[tl * 64 + o] = acc;
    }
  }
  __syncthreads();
  {
    const int m = tid & 127, hf = tid >> 7;
    for (int j = 0; j < 32; ++j) {
      int tl = hf * 32 + j;
      float a0 = 0.f, a1 = 0.f;
#pragma unroll 16
      for (int k = 0; k < 64; ++k) {
        float xv = xe[tl * 64 + k];
        a0 += xv * wh[k * 128 + m];
        a1 += xv * wt[k * 128 + m];
      }
      size_t oidx = (size_t)((b << 8) + tt * 64 + tl) * 128 + m;
      xph[oidx] = a0;
      xpt[oidx] = a1;
    }
  }
}

// ---------------- encoder RHN: one block per batch row ---------------------
__global__ __launch_bounds__(512, 2) void k_encoder(
    const float* __restrict__ xph, const float* __restrict__ xpt,
    const float* __restrict__ RHw, const float* __restrict__ RHb,
    const float* __restrict__ RTw, const float* __restrict__ RTb,
    unsigned short* __restrict__ h_bf) {
  const int b = blockIdx.x;
  const int tid = threadIdx.x;
  const int g = tid >> 8;
  const int m = (tid >> 1) & 127;
  const int hf = tid & 1;
  const float* W = g ? RTw : RHw;
  const float* Bb = g ? RTb : RHb;
  const float* XP = g ? xpt : xph;
  float wreg[3][64];
#pragma unroll
  for (int l = 0; l < 3; ++l)
#pragma unroll
    for (int j = 0; j < 64; ++j)
      wreg[l][j] = W[(size_t)(l * 128 + hf * 64 + j) * 128 + m];
  float bias[3];
#pragma unroll
  for (int l = 0; l < 3; ++l) bias[l] = Bb[l * 128 + m];

  __shared__ float s_lds[128];
  __shared__ float hg[128];
  __shared__ float tg[128];
  if (tid < 128) s_lds[tid] = 0.f;
  __syncthreads();

  for (int t = 0; t < 256; ++t) {
    const float xp = XP[(size_t)((b << 8) + t) * 128 + m];
#pragma unroll
    for (int l = 0; l < 3; ++l) {
      float acc = (hf == 0) ? (bias[l] + (l == 0 ? xp : 0.f)) : 0.f;
      const float* sp = s_lds + hf * 64;
#pragma unroll
      for (int j = 0; j < 64; ++j) acc += sp[j] * wreg[l][j];
      float tot = acc + __shfl_xor(acc, 1);
      if (hf == 0) {
        if (g == 0) hg[m] = tanh_fast(tot);
        else        tg[m] = sigmoid_fast(tot);
      }
      __syncthreads();
      if (tid < 128) {
        float tv = tg[tid];
        float sn = hg[tid] * tv + (1.f - tv) * s_lds[tid];
        s_lds[tid] = sn;
        h_bf[((size_t)(b * 3 + l) * 256 + t) * 128 + tid] = f2bf(sn);
      }
      __syncthreads();
    }
  }
}

// ------ Uh_bf[b][r][t][m] = bf16( h[b][r][t][:] @ Uk_w[r] + Uk_b[r] ) ------
__global__ __launch_bounds__(256) void k_uh(
    const unsigned short* __restrict__ h_bf, const float* __restrict__ Uk_w,
    const float* __restrict__ Uk_b, unsigned short* __restrict__ Uh_bf) {
  __shared__ float wl[128 * 128];  // 64 KB
  __shared__ float hl[32 * 128];   // 16 KB
  const int blk = blockIdx.x;
  const int b = blk / 24;
  const int rem = blk % 24;
  const int r = rem >> 3, tt = rem & 7;
  const int tid = threadIdx.x;
  for (int i = tid; i < 16384; i += 256) wl[i] = Uk_w[(size_t)r * 16384 + i];
  const size_t hbase = ((size_t)(b * 3 + r) * 256 + tt * 32) * 128;
  const ushort8* hv = (const ushort8*)(h_bf + hbase);
  for (int i = tid; i < 512; i += 256) {
    ushort8 u = hv[i];
#pragma unroll
    for (int j = 0; j < 8; ++j) hl[i * 8 + j] = bf2f(u[j]);
  }
  __syncthreads();
  const int m = tid & 127, tr = tid >> 7;
  const float ub = Uk_b[r * 128 + m];
  for (int j = 0; j < 16; ++j) {
    int tl = tr * 16 + j;
    float acc = ub;
#pragma unroll 16
    for (int n = 0; n < 128; ++n) acc += hl[tl * 128 + n] * wl[n * 128 + m];
    Uh_bf[hbase + (size_t)tl * 128 + m] = f2bf(acc);
  }
}

// ---------------- attentive RHN decoder: one block per batch row -----------
// 768 threads. Persistent registers: ureg (Uh row, 64 VGPR) + hreg (h slice,
// 64 VGPR). Tk in LDS (bf16 pairs, XOR-swizzled). Steady-state global
// traffic: only cellw (196 KB, L2-resident, shared across XCD).
__global__ __launch_bounds__(768) void k_decoder(
    const float* __restrict__ y, const unsigned short* __restrict__ Uh_bf,
    const unsigned short* __restrict__ h_bf, const float* __restrict__ Tk_w,
    const float* __restrict__ vk_w, const float* __restrict__ vk_b,
    const float* __restrict__ Wt_w, const float* __restrict__ Vt_w,
    const float* __restrict__ Vt_b,
    const float* __restrict__ WHd, const float* __restrict__ WTd,
    const unsigned short* __restrict__ cellw,
    const float* __restrict__ RHb, const float* __restrict__ RTb,
    const float* __restrict__ W_w, const float* __restrict__ W_b,
    const float* __restrict__ V_w, const float* __restrict__ V_b,
    float* __restrict__ out) {
  const int b = blockIdx.x;
  const int tid = threadIdx.x;

  __shared__ uint32 tk_lds[3 * 128 * 64];  // 96 KiB: packed bf16 n-pairs
  __shared__ __align__(16) float s_lds[128];
  __shared__ __align__(16) float Ts_lds[384];
  __shared__ __align__(16) float a_lds[768];
  __shared__ __align__(16) float d_lds[384];
  __shared__ __align__(16) float vk_lds[384];
  __shared__ __align__(16) float Vt_lds[384];
  __shared__ __align__(16) float dpart[12 * 128];
  __shared__ float cpart[6 * 128];
  __shared__ float hg[128];
  __shared__ float tg[128];
  __shared__ float bias_lds[1024];  // RHb[384] RTb[384] WHd[128] WTd[128]
  __shared__ float y_lds[256];
  __shared__ float red[32];
  __shared__ float ytil_lds;

  const int r3 = tid >> 8;          // 0..2 (wave-uniform)
  const int m2 = (tid >> 1) & 127;
  const int p2 = tid & 1;
  const int t_e = tid & 255;

  // ---- one-time LDS fills ----
  // Tk: [r][n][m] fp32 -> packed pairs tk_lds[r*8192 + m*64 + (j ^ (m&31))]
  for (int i = tid; i < 24576; i += 768) {
    int r = i >> 13, rem = i & 8191, j = rem >> 7, m = rem & 127;
    float g0 = Tk_w[(size_t)r * 16384 + (2 * j) * 128 + m];
    float g1 = Tk_w[(size_t)r * 16384 + (2 * j + 1) * 128 + m];
    tk_lds[r * 8192 + m * 64 + (j ^ (m & 31))] =
        (uint32)f2bf(g0) | ((uint32)f2bf(g1) << 16);
  }
  for (int i = tid; i < 384; i += 768) {
    vk_lds[i] = vk_w[i];
    Vt_lds[i] = Vt_w[i];
    bias_lds[i] = RHb[i];
    bias_lds[384 + i] = RTb[i];
  }
  if (tid < 128) {
    bias_lds[768 + tid] = WHd[tid];
    bias_lds[896 + tid] = WTd[tid];
    s_lds[tid] = 0.f;
  }
  if (tid < 256) y_lds[tid] = y[(b << 8) + tid];
  const float wt0 = Wt_w[0], vtb0 = Vt_b[0];

  // ---- persistent registers ----
  // Uh row for (r3, t_e): 16 x ushort8 = 64 VGPR.
  ushort8 ureg[16];
  {
    const ushort8* up =
        (const ushort8*)(Uh_bf + ((size_t)(b * 3 + r3) * 256 + t_e) * 128);
#pragma unroll
    for (int q = 0; q < 16; ++q) ureg[q] = up[q];
  }
  // h slice for d-phase role (r3, tq, mp): 64 x uint = 64 VGPR.
  const int mp = tid & 63, tq = (tid >> 6) & 3;
  uint32 hreg[64];
  {
    const unsigned short* hb =
        h_bf + ((size_t)(b * 3 + r3) * 256 + tq * 64) * 128 + 2 * mp;
#pragma unroll
    for (int t2 = 0; t2 < 64; ++t2)
      hreg[t2] = *(const uint32*)(hb + (size_t)t2 * 128);
  }
  __syncthreads();

  const float vkb = vk_b[r3];
  const int wv = tid >> 6;  // wave 0..11 (4 waves per r)
  const int lane = tid & 63;
  // cell role: (third=r3, gc, mc); n-split 43/43/42
  const int gc = (tid >> 7) & 1, mc = tid & 127;
  const int n0 = r3 * 43, n1 = (r3 == 2) ? 128 : (r3 * 43 + 43);
  const unsigned short* Wc = cellw + gc * 49152 + mc;
  const uint32* tkp = tk_lds + r3 * 8192 + m2 * 64;
  const int swz = m2 & 31;

  for (int step = 0; step < 256; ++step) {
    // ---- Ts[r][m] = s @ Tk[r] (Tk from LDS, pair-split over n) ----
    {
      float acc = 0.f;
      const float* sp = s_lds + p2 * 64;
      const int jb = p2 * 32;
#pragma unroll 8
      for (int jj = 0; jj < 32; ++jj) {
        uint32 w = tkp[(jb + jj) ^ swz];
        float2 sv = *(const float2*)(sp + 2 * jj);
        acc += sv.x * bf2f_lo(w) + sv.y * bf2f_hi(w);
      }
      float tot = acc + __shfl_xor(acc, 1);
      if (p2 == 0) Ts_lds[r3 * 128 + m2] = tot;
    }
    __syncthreads();  // (1)
    // ---- e[r][t] = vk . tanh(Uh + Ts) + vk_b  (Uh in registers) ----
    {
      const float4* ts4 = (const float4*)(Ts_lds + r3 * 128);
      const float4* vk4 = (const float4*)(vk_lds + r3 * 128);
      float acc0 = 0.f, acc1 = 0.f;
#pragma unroll
      for (int q = 0; q < 16; ++q) {
        ushort8 u = ureg[q];
        float4 t0 = ts4[2 * q], t1 = ts4[2 * q + 1];
        float4 v0 = vk4[2 * q], v1 = vk4[2 * q + 1];
        acc0 += v0.x * tanh_fast(bf2f(u[0]) + t0.x);
        acc1 += v0.y * tanh_fast(bf2f(u[1]) + t0.y);
        acc0 += v0.z * tanh_fast(bf2f(u[2]) + t0.z);
        acc1 += v0.w * tanh_fast(bf2f(u[3]) + t0.w);
        acc0 += v1.x * tanh_fast(bf2f(u[4]) + t1.x);
        acc1 += v1.y * tanh_fast(bf2f(u[5]) + t1.y);
        acc0 += v1.z * tanh_fast(bf2f(u[6]) + t1.z);
        acc1 += v1.w * tanh_fast(bf2f(u[7]) + t1.w);
      }
      a_lds[r3 * 256 + t_e] = acc0 + acc1 + vkb;
    }
    __syncthreads();  // (2)
    // ---- softmax over t (per r) ----
    {
      float e = a_lds[r3 * 256 + t_e];
      float mx = e;
#pragma unroll
      for (int off = 32; off; off >>= 1) mx = fmaxf(mx, __shfl_xor(mx, off));
      if (lane == 0) red[wv] = mx;
      __syncthreads();  // (3)
      const int wb = r3 * 4;
      mx = fmaxf(fmaxf(red[wb], red[wb + 1]), fmaxf(red[wb + 2], red[wb + 3]));
      float p = __expf(e - mx);
      float sm = p;
#pragma unroll
      for (int off = 32; off; off >>= 1) sm += __shfl_xor(sm, off);
      if (lane == 0) red[16 + wv] = sm;
      __syncthreads();  // (4)
      float den =
          red[16 + wb] + red[16 + wb + 1] + red[16 + wb + 2] + red[16 + wb + 3];
      a_lds[r3 * 256 + t_e] = p * rcp_fast(den);
    }
    __syncthreads();  // (5)
    // ---- d partials: alpha . h (h in registers, alpha broadcast) ----
    {
      const float4* ap4 = (const float4*)(a_lds + r3 * 256 + tq * 64);
      float d0 = 0.f, d1 = 0.f;
#pragma unroll
      for (int i4 = 0; i4 < 16; ++i4) {
        float4 a = ap4[i4];
        uint32 u0 = hreg[4 * i4 + 0], u1 = hreg[4 * i4 + 1];
        uint32 u2 = hreg[4 * i4 + 2], u3 = hreg[4 * i4 + 3];
        d0 += a.x * bf2f_lo(u0); d1 += a.x * bf2f_hi(u0);
        d0 += a.y * bf2f_lo(u1); d1 += a.y * bf2f_hi(u1);
        d0 += a.z * bf2f_lo(u2); d1 += a.z * bf2f_hi(u2);
        d0 += a.w * bf2f_lo(u3); d1 += a.w * bf2f_hi(u3);
      }
      *(float2*)(dpart + (r3 * 4 + tq) * 128 + 2 * mp) = {d0, d1};
    }
    __syncthreads();  // (6)
    // ---- combine d + start y_til dot ----
    {
      float part = 0.f;
      if (tid < 384) {
        const int rr = tid >> 7, mm = tid & 127;
        float dv = dpart[(rr * 4 + 0) * 128 + mm] + dpart[(rr * 4 + 1) * 128 + mm] +
                   dpart[(rr * 4 + 2) * 128 + mm] + dpart[(rr * 4 + 3) * 128 + mm];
        d_lds[tid] = dv;
        part = dv * Vt_lds[tid];
      }
#pragma unroll
      for (int off = 32; off; off >>= 1) part += __shfl_xor(part, off);
      if (lane == 0 && wv < 6) red[wv] = part;
    }
    __syncthreads();  // (7)
    if (tid == 0) {
      float tot = red[0] + red[1] + red[2] + red[3] + red[4] + red[5];
      ytil_lds = y_lds[step] * wt0 + tot + vtb0;
    }
    __syncthreads();  // (8)
    // ---- decoder RHN cell (3 micro-steps, bf16 weights from L2) ----
    {
      const float ytil = ytil_lds;
#pragma unroll
      for (int l = 0; l < 3; ++l) {
        {
          float acc = 0.f;
          const unsigned short* wp = Wc + (size_t)(l * 128 + n0) * 128;
          for (int n = n0; n < n1; ++n) {
            acc += s_lds[n] * bf2f(*wp);
            wp += 128;
          }
          cpart[(r3 * 2 + gc) * 128 + mc] = acc;
        }
        __syncthreads();  // cell A
        if (tid < 128) {
          float ha = cpart[0 * 128 + tid] + cpart[2 * 128 + tid] +
                     cpart[4 * 128 + tid] + bias_lds[l * 128 + tid];
          float ta = cpart[1 * 128 + tid] + cpart[3 * 128 + tid] +
                     cpart[5 * 128 + tid] + bias_lds[384 + l * 128 + tid];
          if (l == 0) {
            ha += ytil * bias_lds[768 + tid];
            ta += ytil * bias_lds[896 + tid];
          }
          float hv = tanh_fast(ha);
          float tv = sigmoid_fast(ta);
          s_lds[tid] = hv * tv + (1.f - tv) * s_lds[tid];
        }
        __syncthreads();  // cell B
      }
    }
  }
  // ---- output head: out[b] = s.W_w + W_b + d.V_w + V_b ----
  if (tid < 64) {
    float acc = 0.f;
    for (int i = tid; i < 128; i += 64) acc += s_lds[i] * W_w[i];
    for (int k = tid; k < 384; k += 64) acc += d_lds[k] * V_w[k];
#pragma unroll
    for (int off = 32; off; off >>= 1) acc += __shfl_xor(acc, off);
    if (tid == 0) out[b] = acc + W_b[0] + V_b[0];
  }
}

extern "C" void kernel_launch(void* const* d_in, const int* in_sizes, int n_in,
                              void* d_out, int out_size, void* d_ws,
                              size_t ws_size, hipStream_t stream) {
  (void)in_sizes; (void)n_in; (void)out_size; (void)ws_size;
  const float* x    = (const float*)d_in[0];
  const float* y    = (const float*)d_in[1];
  const float* c0w  = (const float*)d_in[2];
  const float* c0b  = (const float*)d_in[3];
  const float* c1w  = (const float*)d_in[4];
  const float* c1b  = (const float*)d_in[5];
  const float* c2ew = (const float*)d_in[6];
  const float* c2eb = (const float*)d_in[7];
  const float* eWH  = (const float*)d_in[8];
  const float* eWT  = (const float*)d_in[9];
  const float* eRHw = (const float*)d_in[10];
  const float* eRHb = (const float*)d_in[11];
  const float* eRTw = (const float*)d_in[12];
  const float* eRTb = (const float*)d_in[13];
  const float* dWH  = (const float*)d_in[14];
  const float* dWT  = (const float*)d_in[15];
  const float* dRHw = (const float*)d_in[16];
  const float* dRHb = (const float*)d_in[17];
  const float* dRTw = (const float*)d_in[18];
  const float* dRTb = (const float*)d_in[19];
  const float* Tk   = (const float*)d_in[20];
  const float* Ukw  = (const float*)d_in[21];
  const float* Ukb  = (const float*)d_in[22];
  const float* vkw  = (const float*)d_in[23];
  const float* vkb  = (const float*)d_in[24];
  const float* Wtw  = (const float*)d_in[25];
  const float* Vtw  = (const float*)d_in[26];
  const float* Vtb  = (const float*)d_in[27];
  const float* Ww   = (const float*)d_in[28];
  const float* Wb   = (const float*)d_in[29];
  const float* Vw   = (const float*)d_in[30];
  const float* Vb   = (const float*)d_in[31];
  float* out = (float*)d_out;
  float* ws = (float*)d_ws;

  // Workspace layout (float units). Total 37,797,888 floats = 151.2 MB.
  unsigned short* h_bf  = (unsigned short*)ws;
  unsigned short* Uh_bf = (unsigned short*)(ws + 12582912);
  float* xph = ws + 12582912;
  float* xpt = ws + 20971520;
  float* c0o = ws + 29360128;
  float* c1o = ws + 33554432;
  unsigned short* cellw = (unsigned short*)(ws + 37748736);

  k_prep<<<192, 256, 0, stream>>>(dRHw, dRTw, cellw);
  k_conv0<<<1024, 256, 0, stream>>>(x, c0w, c0b, c0o);
  k_conv1<<<1024, 256, 0, stream>>>(c0o, c1w, c1b, c1o);
  k_c2e_proj<<<1024, 256, 0, stream>>>(c1o, c2ew, c2eb, eWH, eWT, xph, xpt);
  k_encoder<<<256, 512, 0, stream>>>(xph, xpt, eRHw, eRHb, eRTw, eRTb, h_bf);
  k_uh<<<6144, 256, 0, stream>>>(h_bf, Ukw, Ukb, Uh_bf);
  k_decoder<<<256, 768, 0, stream>>>(y, Uh_bf, h_bf, Tk, vkw, vkb, Wtw, Vtw,
                                     Vtb, dWH, dWT, cellw, dRHb, dRTb,
                                     Ww, Wb, Vw, Vb, out);
}

// Round 4
// 16154.376 us; speedup vs baseline: 1.2328x; 1.2328x over previous
//
#include <hip/hip_runtime.h>
#include <cstdint>

#define DEV __device__ __forceinline__

typedef unsigned short ushort8 __attribute__((ext_vector_type(8)));
typedef unsigned int uint32;

#if __has_builtin(__builtin_amdgcn_rcpf)
DEV float rcp_fast(float x) { return __builtin_amdgcn_rcpf(x); }
#else
DEV float rcp_fast(float x) { return 1.f / x; }
#endif

// tanh(x) = 1 - 2/(exp(2x)+1): safe at +/-inf (no NaN), ~1e-7 rel err.
DEV float tanh_fast(float x) {
  float z = __expf(2.f * x);
  return 1.f - 2.f * rcp_fast(z + 1.f);
}
DEV float sigmoid_fast(float x) {
  return rcp_fast(1.f + __expf(-x));
}

// bf16 helpers (RTN pack; unpack via bit shift).
DEV unsigned short f2bf(float f) {
  uint32 u = __float_as_uint(f);
  u += 0x7FFFu + ((u >> 16) & 1u);
  return (unsigned short)(u >> 16);
}
DEV float bf2f(unsigned short s) { return __uint_as_float(((uint32)s) << 16); }
DEV float bf2f_lo(uint32 u) { return __uint_as_float(u << 16); }
DEV float bf2f_hi(uint32 u) { return __uint_as_float(u & 0xFFFF0000u); }

// ------- prep: decoder cell weights -> bf16 n-pair-packed dwords -----------
// out[g][l][n2][m] = pack(w[l][2*n2][m], w[l][2*n2+1][m]); g=0:RHw, g=1:RTw.
__global__ __launch_bounds__(256) void k_prep(const float* __restrict__ RHw,
                                              const float* __restrict__ RTw,
                                              uint32* __restrict__ out) {
  int i = blockIdx.x * 256 + threadIdx.x;
  if (i >= 49152) return;
  int g = i / 24576, rem = i % 24576;
  int l = rem / 8192, n2 = (rem >> 7) & 63, m = rem & 127;
  const float* W = g ? RTw : RHw;
  float w0 = W[(size_t)(l * 128 + 2 * n2) * 128 + m];
  float w1 = W[(size_t)(l * 128 + 2 * n2 + 1) * 128 + m];
  out[i] = (uint32)f2bf(w0) | ((uint32)f2bf(w1) << 16);
}

// ---------------- conv0: [B,T,16] -> [B,T,64], k=5 pad=2, +bias, ReLU ------
__global__ __launch_bounds__(256) void k_conv0(
    const float* __restrict__ x, const float* __restrict__ w,
    const float* __restrict__ bias, float* __restrict__ out) {
  __shared__ float wl[16 * 5 * 64];
  __shared__ float xl[68 * 16];
  const int blk = blockIdx.x;
  const int b = blk >> 2, tt = blk & 3;
  const int tid = threadIdx.x;
  for (int i = tid; i < 5120; i += 256) {
    int o = i / 80, rem = i % 80, ii = rem / 5, kk = rem % 5;
    wl[(ii * 5 + kk) * 64 + o] = w[i];
  }
  const int t0 = tt * 64;
  for (int i = tid; i < 68 * 16; i += 256) {
    int row = i >> 4, c = i & 15;
    int t = t0 - 2 + row;
    xl[i] = (t >= 0 && t < 256) ? x[((b << 8) + t) * 16 + c] : 0.f;
  }
  __syncthreads();
  const int o = tid & 63, tr = tid >> 6;
  for (int j = 0; j < 16; ++j) {
    int tl = tr * 16 + j;
    float acc = bias[o];
#pragma unroll
    for (int kk = 0; kk < 5; ++kk)
#pragma unroll
      for (int ii = 0; ii < 16; ++ii)
        acc += xl[(tl + kk) * 16 + ii] * wl[(ii * 5 + kk) * 64 + o];
    out[((b << 8) + t0 + tl) * 64 + o] = fmaxf(acc, 0.f);
  }
}

// ---------------- conv1: [B,T,64] -> [B,T,64], k=5 pad=2, +bias, ReLU ------
__global__ __launch_bounds__(256) void k_conv1(
    const float* __restrict__ in0, const float* __restrict__ w,
    const float* __restrict__ bias, float* __restrict__ out) {
  __shared__ float wl[64 * 5 * 64];  // 80 KB
  __shared__ float xl[68 * 64];      // 17 KB
  const int blk = blockIdx.x;
  const int b = blk >> 2, tt = blk & 3;
  const int tid = threadIdx.x;
  for (int i = tid; i < 64 * 5 * 64; i += 256) {
    int o = i / 320, rem = i % 320, ii = rem / 5, kk = rem % 5;
    wl[(ii * 5 + kk) * 64 + o] = w[i];
  }
  const int t0 = tt * 64;
  for (int i = tid; i < 68 * 64; i += 256) {
    int row = i >> 6, c = i & 63;
    int t = t0 - 2 + row;
    xl[i] = (t >= 0 && t < 256) ? in0[((b << 8) + t) * 64 + c] : 0.f;
  }
  __syncthreads();
  const int o = tid & 63, tr = tid >> 6;
  for (int j = 0; j < 16; ++j) {
    int tl = tr * 16 + j;
    float acc = bias[o];
    for (int kk = 0; kk < 5; ++kk) {
#pragma unroll 16
      for (int ii = 0; ii < 64; ++ii)
        acc += xl[(tl + kk) * 64 + ii] * wl[(ii * 5 + kk) * 64 + o];
    }
    out[((b << 8) + t0 + tl) * 64 + o] = fmaxf(acc, 0.f);
  }
}

// --------- c2e (+bias) fused with encoder input projections x@WH, x@WT -----
__global__ __launch_bounds__(256) void k_c2e_proj(
    const float* __restrict__ in1, const float* __restrict__ cw,
    const float* __restrict__ cb, const float* __restrict__ WH,
    const float* __restrict__ WT, float* __restrict__ xph,
    float* __restrict__ xpt) {
  __shared__ float xin[64 * 64];
  __shared__ float w1[64 * 64];
  __shared__ float xe[64 * 64];
  __shared__ float wh[64 * 128];
  __shared__ float wt[64 * 128];
  const int blk = blockIdx.x;
  const int b = blk >> 2, tt = blk & 3;
  const int tid = threadIdx.x;
  for (int i = tid; i < 4096; i += 256) {
    xin[i] = in1[(size_t)(((b << 8) + tt * 64)) * 64 + i];
    w1[i] = cw[i];
  }
  for (int i = tid; i < 8192; i += 256) {
    wh[i] = WH[i];
    wt[i] = WT[i];
  }
  __syncthreads();
  {
    const int o = tid & 63, tr = tid >> 6;
    for (int j = 0; j < 16; ++j) {
      int tl = tr * 16 + j;
      float acc = cb[o];
#pragma unroll 16
      for (int k = 0; k < 64; ++k) acc += xin[tl * 64 + k] * w1[k * 64 + o];
      xe[tl * 64 + o] = acc;
    }
  }
  __syncthreads();
  {
    const int m = tid & 127, hf = tid >> 7;
    for (int j = 0; j < 32; ++j) {
      int tl = hf * 32 + j;
      float a0 = 0.f, a1 = 0.f;
#pragma unroll 16
      for (int k = 0; k < 64; ++k) {
        float xv = xe[tl * 64 + k];
        a0 += xv * wh[k * 128 + m];
        a1 += xv * wt[k * 128 + m];
      }
      size_t oidx = (size_t)((b << 8) + tt * 64 + tl) * 128 + m;
      xph[oidx] = a0;
      xpt[oidx] = a1;
    }
  }
}

// ---------------- encoder RHN: one block per batch row ---------------------
__global__ __launch_bounds__(512, 2) void k_encoder(
    const float* __restrict__ xph, const float* __restrict__ xpt,
    const float* __restrict__ RHw, const float* __restrict__ RHb,
    const float* __restrict__ RTw, const float* __restrict__ RTb,
    unsigned short* __restrict__ h_bf) {
  const int b = blockIdx.x;
  const int tid = threadIdx.x;
  const int g = tid >> 8;
  const int m = (tid >> 1) & 127;
  const int hf = tid & 1;
  const float* W = g ? RTw : RHw;
  const float* Bb = g ? RTb : RHb;
  const float* XP = g ? xpt : xph;
  float wreg[3][64];
#pragma unroll
  for (int l = 0; l < 3; ++l)
#pragma unroll
    for (int j = 0; j < 64; ++j)
      wreg[l][j] = W[(size_t)(l * 128 + hf * 64 + j) * 128 + m];
  float bias[3];
#pragma unroll
  for (int l = 0; l < 3; ++l) bias[l] = Bb[l * 128 + m];

  __shared__ float s_lds[128];
  __shared__ float hg[128];
  __shared__ float tg[128];
  if (tid < 128) s_lds[tid] = 0.f;
  __syncthreads();

  for (int t = 0; t < 256; ++t) {
    const float xp = XP[(size_t)((b << 8) + t) * 128 + m];
#pragma unroll
    for (int l = 0; l < 3; ++l) {
      float acc = (hf == 0) ? (bias[l] + (l == 0 ? xp : 0.f)) : 0.f;
      const float* sp = s_lds + hf * 64;
#pragma unroll
      for (int j = 0; j < 64; ++j) acc += sp[j] * wreg[l][j];
      float tot = acc + __shfl_xor(acc, 1);
      if (hf == 0) {
        if (g == 0) hg[m] = tanh_fast(tot);
        else        tg[m] = sigmoid_fast(tot);
      }
      __syncthreads();
      if (tid < 128) {
        float tv = tg[tid];
        float sn = hg[tid] * tv + (1.f - tv) * s_lds[tid];
        s_lds[tid] = sn;
        h_bf[((size_t)(b * 3 + l) * 256 + t) * 128 + tid] = f2bf(sn);
      }
      __syncthreads();
    }
  }
}

// ------ Uh_bf[b][r][t][m] = bf16( h[b][r][t][:] @ Uk_w[r] + Uk_b[r] ) ------
__global__ __launch_bounds__(256) void k_uh(
    const unsigned short* __restrict__ h_bf, const float* __restrict__ Uk_w,
    const float* __restrict__ Uk_b, unsigned short* __restrict__ Uh_bf) {
  __shared__ float wl[128 * 128];  // 64 KB
  __shared__ float hl[32 * 128];   // 16 KB
  const int blk = blockIdx.x;
  const int b = blk / 24;
  const int rem = blk % 24;
  const int r = rem >> 3, tt = rem & 7;
  const int tid = threadIdx.x;
  for (int i = tid; i < 16384; i += 256) wl[i] = Uk_w[(size_t)r * 16384 + i];
  const size_t hbase = ((size_t)(b * 3 + r) * 256 + tt * 32) * 128;
  const ushort8* hv = (const ushort8*)(h_bf + hbase);
  for (int i = tid; i < 512; i += 256) {
    ushort8 u = hv[i];
#pragma unroll
    for (int j = 0; j < 8; ++j) hl[i * 8 + j] = bf2f(u[j]);
  }
  __syncthreads();
  const int m = tid & 127, tr = tid >> 7;
  const float ub = Uk_b[r * 128 + m];
  for (int j = 0; j < 16; ++j) {
    int tl = tr * 16 + j;
    float acc = ub;
#pragma unroll 16
    for (int n = 0; n < 128; ++n) acc += hl[tl * 128 + n] * wl[n * 128 + m];
    Uh_bf[hbase + (size_t)tl * 128 + m] = f2bf(acc);
  }
}

// ---------------- attentive RHN decoder: one block per batch row -----------
// 768 threads, 1 block/CU (LDS-limited) = 3 waves/EU; amdgpu_waves_per_eu
// pins the VGPR budget at 168 so the 128 persistent regs (ureg32+hreg) stay
// resident. Empty "+v" asm makes global-reload rematerialization illegal.
__global__ __launch_bounds__(768)
__attribute__((amdgpu_waves_per_eu(3, 3))) void k_decoder(
    const float* __restrict__ y, const unsigned short* __restrict__ Uh_bf,
    const unsigned short* __restrict__ h_bf, const float* __restrict__ Tk_w,
    const float* __restrict__ vk_w, const float* __restrict__ vk_b,
    const float* __restrict__ Wt_w, const float* __restrict__ Vt_w,
    const float* __restrict__ Vt_b,
    const float* __restrict__ WHd, const float* __restrict__ WTd,
    const uint32* __restrict__ cellw,
    const float* __restrict__ RHb, const float* __restrict__ RTb,
    const float* __restrict__ W_w, const float* __restrict__ W_b,
    const float* __restrict__ V_w, const float* __restrict__ V_b,
    float* __restrict__ out) {
  const int b = blockIdx.x;
  const int tid = threadIdx.x;

  __shared__ uint32 tk_lds[3 * 128 * 64];  // 96 KiB: packed bf16 n-pairs
  __shared__ __align__(16) float s_lds[128];
  __shared__ __align__(16) float Ts_lds[384];
  __shared__ __align__(16) float a_lds[768];
  __shared__ __align__(16) float d_lds[384];
  __shared__ __align__(16) float vk_lds[384];
  __shared__ __align__(16) float Vt_lds[384];
  __shared__ __align__(16) float dpart[12 * 128];
  __shared__ float cpart[6 * 128];
  __shared__ float bias_lds[1024];  // RHb[384] RTb[384] WHd[128] WTd[128]
  __shared__ float y_lds[256];
  __shared__ float red[32];
  __shared__ float ytil_lds;

  const int r3 = tid >> 8;          // 0..2 (wave-uniform)
  const int m2 = (tid >> 1) & 127;
  const int p2 = tid & 1;
  const int t_e = tid & 255;

  // ---- one-time LDS fills ----
  // Tk: [r][n][m] fp32 -> packed pairs tk_lds[r*8192 + m*64 + (j ^ (m&31))]
  for (int i = tid; i < 24576; i += 768) {
    int r = i >> 13, rem = i & 8191, j = rem >> 7, m = rem & 127;
    float g0 = Tk_w[(size_t)r * 16384 + (2 * j) * 128 + m];
    float g1 = Tk_w[(size_t)r * 16384 + (2 * j + 1) * 128 + m];
    tk_lds[r * 8192 + m * 64 + (j ^ (m & 31))] =
        (uint32)f2bf(g0) | ((uint32)f2bf(g1) << 16);
  }
  for (int i = tid; i < 384; i += 768) {
    vk_lds[i] = vk_w[i];
    Vt_lds[i] = Vt_w[i];
    bias_lds[i] = RHb[i];
    bias_lds[384 + i] = RTb[i];
  }
  if (tid < 128) {
    bias_lds[768 + tid] = WHd[tid];
    bias_lds[896 + tid] = WTd[tid];
    s_lds[tid] = 0.f;
  }
  if (tid < 256) y_lds[tid] = y[(b << 8) + tid];
  const float wt0 = Wt_w[0], vtb0 = Vt_b[0];

  // ---- persistent registers ----
  // Uh row for (r3, t_e): 64 packed dwords = 64 VGPR.
  uint32 ureg32[64];
  {
    const uint4* up =
        (const uint4*)(Uh_bf + ((size_t)(b * 3 + r3) * 256 + t_e) * 128);
#pragma unroll
    for (int q = 0; q < 16; ++q) {
      uint4 v = up[q];
      ureg32[4 * q + 0] = v.x;
      ureg32[4 * q + 1] = v.y;
      ureg32[4 * q + 2] = v.z;
      ureg32[4 * q + 3] = v.w;
    }
  }
  // h slice for d-phase role (r3, tq, mp): 64 packed dwords = 64 VGPR.
  const int mp = tid & 63, tq = (tid >> 6) & 3;
  uint32 hreg[64];
  {
    const unsigned short* hb =
        h_bf + ((size_t)(b * 3 + r3) * 256 + tq * 64) * 128 + 2 * mp;
#pragma unroll
    for (int t2 = 0; t2 < 64; ++t2)
      hreg[t2] = *(const uint32*)(hb + (size_t)t2 * 128);
  }
  // Forbid reload-rematerialization: values nominally diverge from memory.
#pragma unroll
  for (int q = 0; q < 64; ++q) asm volatile("" : "+v"(ureg32[q]));
#pragma unroll
  for (int q = 0; q < 64; ++q) asm volatile("" : "+v"(hreg[q]));
  __syncthreads();

  const float vkb = vk_b[r3];
  const int wv = tid >> 6;  // wave 0..11 (4 waves per r)
  const int lane = tid & 63;
  // cell role: (third=r3, gc, mc); n2-split 21/21/22 over 64 pair-rows
  const int gc = (tid >> 7) & 1, mc = tid & 127;
  const int q0 = r3 * 21, q1 = (r3 == 2) ? 64 : (r3 * 21 + 21);
  const uint32* Wc = cellw + gc * 24576 + mc;
  const uint32* tkp = tk_lds + r3 * 8192 + m2 * 64;
  const int swz = m2 & 31;

  for (int step = 0; step < 256; ++step) {
    // ---- Ts[r][m] = s @ Tk[r] (Tk from LDS, pair-split over n) ----
    {
      float acc = 0.f;
      const float* sp = s_lds + p2 * 64;
      const int jb = p2 * 32;
#pragma unroll 8
      for (int jj = 0; jj < 32; ++jj) {
        uint32 w = tkp[(jb + jj) ^ swz];
        float2 sv = *(const float2*)(sp + 2 * jj);
        acc += sv.x * bf2f_lo(w) + sv.y * bf2f_hi(w);
      }
      float tot = acc + __shfl_xor(acc, 1);
      if (p2 == 0) Ts_lds[r3 * 128 + m2] = tot;
    }
    __syncthreads();  // (1)
    // ---- e[r][t] = vk . tanh(Uh + Ts) + vk_b  (Uh in registers) ----
    {
      const float4* ts4 = (const float4*)(Ts_lds + r3 * 128);
      const float4* vk4 = (const float4*)(vk_lds + r3 * 128);
      float acc0 = 0.f, acc1 = 0.f;
#pragma unroll
      for (int q = 0; q < 32; ++q) {
        uint32 w0 = ureg32[2 * q], w1 = ureg32[2 * q + 1];
        float4 t0 = ts4[q];
        float4 v0 = vk4[q];
        acc0 += v0.x * tanh_fast(bf2f_lo(w0) + t0.x);
        acc1 += v0.y * tanh_fast(bf2f_hi(w0) + t0.y);
        acc0 += v0.z * tanh_fast(bf2f_lo(w1) + t0.z);
        acc1 += v0.w * tanh_fast(bf2f_hi(w1) + t0.w);
      }
      a_lds[r3 * 256 + t_e] = acc0 + acc1 + vkb;
    }
    __syncthreads();  // (2)
    // ---- softmax over t (per r) ----
    {
      float e = a_lds[r3 * 256 + t_e];
      float mx = e;
#pragma unroll
      for (int off = 32; off; off >>= 1) mx = fmaxf(mx, __shfl_xor(mx, off));
      if (lane == 0) red[wv] = mx;
      __syncthreads();  // (3)
      const int wb = r3 * 4;
      mx = fmaxf(fmaxf(red[wb], red[wb + 1]), fmaxf(red[wb + 2], red[wb + 3]));
      float p = __expf(e - mx);
      float sm = p;
#pragma unroll
      for (int off = 32; off; off >>= 1) sm += __shfl_xor(sm, off);
      if (lane == 0) red[16 + wv] = sm;
      __syncthreads();  // (4)
      float den =
          red[16 + wb] + red[16 + wb + 1] + red[16 + wb + 2] + red[16 + wb + 3];
      a_lds[r3 * 256 + t_e] = p * rcp_fast(den);
    }
    __syncthreads();  // (5)
    // ---- d partials: alpha . h (h in registers, alpha broadcast) ----
    {
      const float4* ap4 = (const float4*)(a_lds + r3 * 256 + tq * 64);
      float d0 = 0.f, d1 = 0.f;
#pragma unroll
      for (int i4 = 0; i4 < 16; ++i4) {
        float4 a = ap4[i4];
        uint32 u0 = hreg[4 * i4 + 0], u1 = hreg[4 * i4 + 1];
        uint32 u2 = hreg[4 * i4 + 2], u3 = hreg[4 * i4 + 3];
        d0 += a.x * bf2f_lo(u0); d1 += a.x * bf2f_hi(u0);
        d0 += a.y * bf2f_lo(u1); d1 += a.y * bf2f_hi(u1);
        d0 += a.z * bf2f_lo(u2); d1 += a.z * bf2f_hi(u2);
        d0 += a.w * bf2f_lo(u3); d1 += a.w * bf2f_hi(u3);
      }
      *(float2*)(dpart + (r3 * 4 + tq) * 128 + 2 * mp) = {d0, d1};
    }
    __syncthreads();  // (6)
    // ---- combine d + start y_til dot ----
    {
      float part = 0.f;
      if (tid < 384) {
        const int rr = tid >> 7, mm = tid & 127;
        float dv = dpart[(rr * 4 + 0) * 128 + mm] + dpart[(rr * 4 + 1) * 128 + mm] +
                   dpart[(rr * 4 + 2) * 128 + mm] + dpart[(rr * 4 + 3) * 128 + mm];
        d_lds[tid] = dv;
        part = dv * Vt_lds[tid];
      }
#pragma unroll
      for (int off = 32; off; off >>= 1) part += __shfl_xor(part, off);
      if (lane == 0 && wv < 6) red[wv] = part;
    }
    __syncthreads();  // (7)
    if (tid == 0) {
      float tot = red[0] + red[1] + red[2] + red[3] + red[4] + red[5];
      ytil_lds = y_lds[step] * wt0 + tot + vtb0;
    }
    __syncthreads();  // (8)
    // ---- decoder RHN cell (3 micro-steps, packed bf16 weights from L2) ----
    {
      const float ytil = ytil_lds;
      const float2* sp2 = (const float2*)s_lds;
#pragma unroll
      for (int l = 0; l < 3; ++l) {
        {
          float acc = 0.f;
          const uint32* wp = Wc + (size_t)(l * 64 + q0) * 128;
          for (int n2 = q0; n2 < q1; ++n2) {
            uint32 w = *wp;
            wp += 128;
            float2 sv = sp2[n2];
            acc += sv.x * bf2f_lo(w) + sv.y * bf2f_hi(w);
          }
          cpart[(r3 * 2 + gc) * 128 + mc] = acc;
        }
        __syncthreads();  // cell A
        if (tid < 128) {
          float ha = cpart[0 * 128 + tid] + cpart[2 * 128 + tid] +
                     cpart[4 * 128 + tid] + bias_lds[l * 128 + tid];
          float ta = cpart[1 * 128 + tid] + cpart[3 * 128 + tid] +
                     cpart[5 * 128 + tid] + bias_lds[384 + l * 128 + tid];
          if (l == 0) {
            ha += ytil * bias_lds[768 + tid];
            ta += ytil * bias_lds[896 + tid];
          }
          float hv = tanh_fast(ha);
          float tv = sigmoid_fast(ta);
          s_lds[tid] = hv * tv + (1.f - tv) * s_lds[tid];
        }
        __syncthreads();  // cell B
      }
    }
  }
  // ---- output head: out[b] = s.W_w + W_b + d.V_w + V_b ----
  if (tid < 64) {
    float acc = 0.f;
    for (int i = tid; i < 128; i += 64) acc += s_lds[i] * W_w[i];
    for (int k = tid; k < 384; k += 64) acc += d_lds[k] * V_w[k];
#pragma unroll
    for (int off = 32; off; off >>= 1) acc += __shfl_xor(acc, off);
    if (tid == 0) out[b] = acc + W_b[0] + V_b[0];
  }
}

extern "C" void kernel_launch(void* const* d_in, const int* in_sizes, int n_in,
                              void* d_out, int out_size, void* d_ws,
                              size_t ws_size, hipStream_t stream) {
  (void)in_sizes; (void)n_in; (void)out_size; (void)ws_size;
  const float* x    = (const float*)d_in[0];
  const float* y    = (const float*)d_in[1];
  const float* c0w  = (const float*)d_in[2];
  const float* c0b  = (const float*)d_in[3];
  const float* c1w  = (const float*)d_in[4];
  const float* c1b  = (const float*)d_in[5];
  const float* c2ew = (const float*)d_in[6];
  const float* c2eb = (const float*)d_in[7];
  const float* eWH  = (const float*)d_in[8];
  const float* eWT  = (const float*)d_in[9];
  const float* eRHw = (const float*)d_in[10];
  const float* eRHb = (const float*)d_in[11];
  const float* eRTw = (const float*)d_in[12];
  const float* eRTb = (const float*)d_in[13];
  const float* dWH  = (const float*)d_in[14];
  const float* dWT  = (const float*)d_in[15];
  const float* dRHw = (const float*)d_in[16];
  const float* dRHb = (const float*)d_in[17];
  const float* dRTw = (const float*)d_in[18];
  const float* dRTb = (const float*)d_in[19];
  const float* Tk   = (const float*)d_in[20];
  const float* Ukw  = (const float*)d_in[21];
  const float* Ukb  = (const float*)d_in[22];
  const float* vkw  = (const float*)d_in[23];
  const float* vkb  = (const float*)d_in[24];
  const float* Wtw  = (const float*)d_in[25];
  const float* Vtw  = (const float*)d_in[26];
  const float* Vtb  = (const float*)d_in[27];
  const float* Ww   = (const float*)d_in[28];
  const float* Wb   = (const float*)d_in[29];
  const float* Vw   = (const float*)d_in[30];
  const float* Vb   = (const float*)d_in[31];
  float* out = (float*)d_out;
  float* ws = (float*)d_ws;

  // Workspace layout (float units). Total 37,797,888 floats = 151.2 MB.
  unsigned short* h_bf  = (unsigned short*)ws;
  unsigned short* Uh_bf = (unsigned short*)(ws + 12582912);
  float* xph = ws + 12582912;
  float* xpt = ws + 20971520;
  float* c0o = ws + 29360128;
  float* c1o = ws + 33554432;
  uint32* cellw = (uint32*)(ws + 37748736);

  k_prep<<<192, 256, 0, stream>>>(dRHw, dRTw, cellw);
  k_conv0<<<1024, 256, 0, stream>>>(x, c0w, c0b, c0o);
  k_conv1<<<1024, 256, 0, stream>>>(c0o, c1w, c1b, c1o);
  k_c2e_proj<<<1024, 256, 0, stream>>>(c1o, c2ew, c2eb, eWH, eWT, xph, xpt);
  k_encoder<<<256, 512, 0, stream>>>(xph, xpt, eRHw, eRHb, eRTw, eRTb, h_bf);
  k_uh<<<6144, 256, 0, stream>>>(h_bf, Ukw, Ukb, Uh_bf);
  k_decoder<<<256, 768, 0, stream>>>(y, Uh_bf, h_bf, Tk, vkw, vkb, Wtw, Vtw,
                                     Vtb, dWH, dWT, cellw, dRHb, dRTb,
                                     Ww, Wb, Vw, Vb, out);
}

// Round 5
// 5354.241 us; speedup vs baseline: 3.7195x; 3.0171x over previous
//
#include <hip/hip_runtime.h>
#include <cstdint>

#define DEV __device__ __forceinline__

typedef unsigned short ushort8 __attribute__((ext_vector_type(8)));
typedef unsigned int uint32;

#if __has_builtin(__builtin_amdgcn_rcpf)
DEV float rcp_fast(float x) { return __builtin_amdgcn_rcpf(x); }
#else
DEV float rcp_fast(float x) { return 1.f / x; }
#endif
#if __has_builtin(__builtin_amdgcn_exp2f)
DEV float exp2_fast(float x) { return __builtin_amdgcn_exp2f(x); }
#else
DEV float exp2_fast(float x) { return exp2f(x); }
#endif

// tanh(x) = 1 - 2/(2^(2x*log2e)+1): 5 VALU ops, safe at +/-inf.
DEV float tanh_fast(float x) {
  float z = exp2_fast(x * 2.8853900817779268f);
  return 1.f - 2.f * rcp_fast(z + 1.f);
}
DEV float sigmoid_fast(float x) {
  return rcp_fast(1.f + exp2_fast(-1.4426950408889634f * x));
}

// bf16 helpers (RTN pack; unpack via bit shift).
DEV unsigned short f2bf(float f) {
  uint32 u = __float_as_uint(f);
  u += 0x7FFFu + ((u >> 16) & 1u);
  return (unsigned short)(u >> 16);
}
DEV float bf2f(unsigned short s) { return __uint_as_float(((uint32)s) << 16); }
DEV float bf2f_lo(uint32 u) { return __uint_as_float(u << 16); }
DEV float bf2f_hi(uint32 u) { return __uint_as_float(u & 0xFFFF0000u); }

// ------- prep: decoder cell weights -> bf16 n-pair-packed dwords -----------
__global__ __launch_bounds__(256) void k_prep(const float* __restrict__ RHw,
                                              const float* __restrict__ RTw,
                                              uint32* __restrict__ out) {
  int i = blockIdx.x * 256 + threadIdx.x;
  if (i >= 49152) return;
  int g = i / 24576, rem = i % 24576;
  int l = rem / 8192, n2 = (rem >> 7) & 63, m = rem & 127;
  const float* W = g ? RTw : RHw;
  float w0 = W[(size_t)(l * 128 + 2 * n2) * 128 + m];
  float w1 = W[(size_t)(l * 128 + 2 * n2 + 1) * 128 + m];
  out[i] = (uint32)f2bf(w0) | ((uint32)f2bf(w1) << 16);
}

// ---------------- conv0: [B,T,16] -> [B,T,64], k=5 pad=2, +bias, ReLU ------
__global__ __launch_bounds__(256) void k_conv0(
    const float* __restrict__ x, const float* __restrict__ w,
    const float* __restrict__ bias, float* __restrict__ out) {
  __shared__ float wl[16 * 5 * 64];
  __shared__ float xl[68 * 16];
  const int blk = blockIdx.x;
  const int b = blk >> 2, tt = blk & 3;
  const int tid = threadIdx.x;
  for (int i = tid; i < 5120; i += 256) {
    int o = i / 80, rem = i % 80, ii = rem / 5, kk = rem % 5;
    wl[(ii * 5 + kk) * 64 + o] = w[i];
  }
  const int t0 = tt * 64;
  for (int i = tid; i < 68 * 16; i += 256) {
    int row = i >> 4, c = i & 15;
    int t = t0 - 2 + row;
    xl[i] = (t >= 0 && t < 256) ? x[((b << 8) + t) * 16 + c] : 0.f;
  }
  __syncthreads();
  const int o = tid & 63, tr = tid >> 6;
  for (int j = 0; j < 16; ++j) {
    int tl = tr * 16 + j;
    float acc = bias[o];
#pragma unroll
    for (int kk = 0; kk < 5; ++kk)
#pragma unroll
      for (int ii = 0; ii < 16; ++ii)
        acc += xl[(tl + kk) * 16 + ii] * wl[(ii * 5 + kk) * 64 + o];
    out[((b << 8) + t0 + tl) * 64 + o] = fmaxf(acc, 0.f);
  }
}

// ---------------- conv1: [B,T,64] -> [B,T,64], k=5 pad=2, +bias, ReLU ------
__global__ __launch_bounds__(256) void k_conv1(
    const float* __restrict__ in0, const float* __restrict__ w,
    const float* __restrict__ bias, float* __restrict__ out) {
  __shared__ float wl[64 * 5 * 64];  // 80 KB
  __shared__ float xl[68 * 64];      // 17 KB
  const int blk = blockIdx.x;
  const int b = blk >> 2, tt = blk & 3;
  const int tid = threadIdx.x;
  for (int i = tid; i < 64 * 5 * 64; i += 256) {
    int o = i / 320, rem = i % 320, ii = rem / 5, kk = rem % 5;
    wl[(ii * 5 + kk) * 64 + o] = w[i];
  }
  const int t0 = tt * 64;
  for (int i = tid; i < 68 * 64; i += 256) {
    int row = i >> 6, c = i & 63;
    int t = t0 - 2 + row;
    xl[i] = (t >= 0 && t < 256) ? in0[((b << 8) + t) * 64 + c] : 0.f;
  }
  __syncthreads();
  const int o = tid & 63, tr = tid >> 6;
  for (int j = 0; j < 16; ++j) {
    int tl = tr * 16 + j;
    float acc = bias[o];
    for (int kk = 0; kk < 5; ++kk) {
#pragma unroll 16
      for (int ii = 0; ii < 64; ++ii)
        acc += xl[(tl + kk) * 64 + ii] * wl[(ii * 5 + kk) * 64 + o];
    }
    out[((b << 8) + t0 + tl) * 64 + o] = fmaxf(acc, 0.f);
  }
}

// --------- c2e (+bias) fused with encoder input projections x@WH, x@WT -----
__global__ __launch_bounds__(256) void k_c2e_proj(
    const float* __restrict__ in1, const float* __restrict__ cw,
    const float* __restrict__ cb, const float* __restrict__ WH,
    const float* __restrict__ WT, float* __restrict__ xph,
    float* __restrict__ xpt) {
  __shared__ float xin[64 * 64];
  __shared__ float w1[64 * 64];
  __shared__ float xe[64 * 64];
  __shared__ float wh[64 * 128];
  __shared__ float wt[64 * 128];
  const int blk = blockIdx.x;
  const int b = blk >> 2, tt = blk & 3;
  const int tid = threadIdx.x;
  for (int i = tid; i < 4096; i += 256) {
    xin[i] = in1[(size_t)(((b << 8) + tt * 64)) * 64 + i];
    w1[i] = cw[i];
  }
  for (int i = tid; i < 8192; i += 256) {
    wh[i] = WH[i];
    wt[i] = WT[i];
  }
  __syncthreads();
  {
    const int o = tid & 63, tr = tid >> 6;
    for (int j = 0; j < 16; ++j) {
      int tl = tr * 16 + j;
      float acc = cb[o];
#pragma unroll 16
      for (int k = 0; k < 64; ++k) acc += xin[tl * 64 + k] * w1[k * 64 + o];
      xe[tl * 64 + o] = acc;
    }
  }
  __syncthreads();
  {
    const int m = tid & 127, hf = tid >> 7;
    for (int j = 0; j < 32; ++j) {
      int tl = hf * 32 + j;
      float a0 = 0.f, a1 = 0.f;
#pragma unroll 16
      for (int k = 0; k < 64; ++k) {
        float xv = xe[tl * 64 + k];
        a0 += xv * wh[k * 128 + m];
        a1 += xv * wt[k * 128 + m];
      }
      size_t oidx = (size_t)((b << 8) + tt * 64 + tl) * 128 + m;
      xph[oidx] = a0;
      xpt[oidx] = a1;
    }
  }
}

// ---------------- encoder RHN: one block per batch row ---------------------
__global__ __launch_bounds__(512, 2) void k_encoder(
    const float* __restrict__ xph, const float* __restrict__ xpt,
    const float* __restrict__ RHw, const float* __restrict__ RHb,
    const float* __restrict__ RTw, const float* __restrict__ RTb,
    unsigned short* __restrict__ h_bf) {
  const int b = blockIdx.x;
  const int tid = threadIdx.x;
  const int g = tid >> 8;
  const int m = (tid >> 1) & 127;
  const int hf = tid & 1;
  const float* W = g ? RTw : RHw;
  const float* Bb = g ? RTb : RHb;
  const float* XP = g ? xpt : xph;
  float wreg[3][64];
#pragma unroll
  for (int l = 0; l < 3; ++l)
#pragma unroll
    for (int j = 0; j < 64; ++j)
      wreg[l][j] = W[(size_t)(l * 128 + hf * 64 + j) * 128 + m];
  float bias[3];
#pragma unroll
  for (int l = 0; l < 3; ++l) bias[l] = Bb[l * 128 + m];

  __shared__ float s_lds[128];
  __shared__ float hg[128];
  __shared__ float tg[128];
  if (tid < 128) s_lds[tid] = 0.f;
  __syncthreads();

  for (int t = 0; t < 256; ++t) {
    const float xp = XP[(size_t)((b << 8) + t) * 128 + m];
#pragma unroll
    for (int l = 0; l < 3; ++l) {
      float acc = (hf == 0) ? (bias[l] + (l == 0 ? xp : 0.f)) : 0.f;
      const float* sp = s_lds + hf * 64;
#pragma unroll
      for (int j = 0; j < 64; ++j) acc += sp[j] * wreg[l][j];
      float tot = acc + __shfl_xor(acc, 1);
      if (hf == 0) {
        if (g == 0) hg[m] = tanh_fast(tot);
        else        tg[m] = sigmoid_fast(tot);
      }
      __syncthreads();
      if (tid < 128) {
        float tv = tg[tid];
        float sn = hg[tid] * tv + (1.f - tv) * s_lds[tid];
        s_lds[tid] = sn;
        h_bf[((size_t)(b * 3 + t) * 0 + ((size_t)(b * 3 + l) * 256 + t)) * 128 + tid] = f2bf(sn);
      }
      __syncthreads();
    }
  }
}

// ------ Uh_bf[b][r][t][m] = bf16( h[b][r][t][:] @ Uk_w[r] + Uk_b[r] ) ------
__global__ __launch_bounds__(256) void k_uh(
    const unsigned short* __restrict__ h_bf, const float* __restrict__ Uk_w,
    const float* __restrict__ Uk_b, unsigned short* __restrict__ Uh_bf) {
  __shared__ float wl[128 * 128];  // 64 KB
  __shared__ float hl[32 * 128];   // 16 KB
  const int blk = blockIdx.x;
  const int b = blk / 24;
  const int rem = blk % 24;
  const int r = rem >> 3, tt = rem & 7;
  const int tid = threadIdx.x;
  for (int i = tid; i < 16384; i += 256) wl[i] = Uk_w[(size_t)r * 16384 + i];
  const size_t hbase = ((size_t)(b * 3 + r) * 256 + tt * 32) * 128;
  const ushort8* hv = (const ushort8*)(h_bf + hbase);
  for (int i = tid; i < 512; i += 256) {
    ushort8 u = hv[i];
#pragma unroll
    for (int j = 0; j < 8; ++j) hl[i * 8 + j] = bf2f(u[j]);
  }
  __syncthreads();
  const int m = tid & 127, tr = tid >> 7;
  const float ub = Uk_b[r * 128 + m];
  for (int j = 0; j < 16; ++j) {
    int tl = tr * 16 + j;
    float acc = ub;
#pragma unroll 16
    for (int n = 0; n < 128; ++n) acc += hl[tl * 128 + n] * wl[n * 128 + m];
    Uh_bf[hbase + (size_t)tl * 128 + m] = f2bf(acc);
  }
}

// ------ hv[b][r][t] = h[b][r][t][:].Vt_w[r];  hv2 likewise with V_w --------
__global__ __launch_bounds__(768) void k_hv(
    const unsigned short* __restrict__ h_bf, const float* __restrict__ Vt_w,
    const float* __restrict__ V_w, float* __restrict__ hv,
    float* __restrict__ hv2) {
  __shared__ float vt[384], vw[384];
  const int b = blockIdx.x, tid = threadIdx.x;
  if (tid < 384) {
    vt[tid] = Vt_w[tid];
    vw[tid] = V_w[tid];
  }
  __syncthreads();
  const int r = tid >> 8;
  const uint2* hp = (const uint2*)(h_bf + ((size_t)b * 768 + tid) * 128);
  const float* vtp = vt + r * 128;
  const float* vwp = vw + r * 128;
  float a1 = 0.f, a2 = 0.f;
#pragma unroll 8
  for (int q = 0; q < 32; ++q) {
    uint2 u = hp[q];
    int m = q * 4;
    float h0 = bf2f_lo(u.x), h1 = bf2f_hi(u.x);
    float h2 = bf2f_lo(u.y), h3 = bf2f_hi(u.y);
    a1 += vtp[m] * h0 + vtp[m + 1] * h1 + vtp[m + 2] * h2 + vtp[m + 3] * h3;
    a2 += vwp[m] * h0 + vwp[m + 1] * h1 + vwp[m + 2] * h2 + vwp[m + 3] * h3;
  }
  hv[(size_t)b * 768 + tid] = a1;
  hv2[(size_t)b * 768 + tid] = a2;
}

// ---------------- attentive RHN decoder: one block per batch row -----------
// 1024 threads; thread (t', quarter) holds 48 persistent Uh dwords (3r x 16).
// d-vector is never materialized: d.Vt == sum_r num[r]/den[r] with
// num = sum_t p*hv, den = sum_t p (hv precomputed). No max-sub needed:
// |e| <= ~13 so exp stays in fp32 range.
__global__ __launch_bounds__(1024, 4) void k_decoder(
    const float* __restrict__ y, const unsigned short* __restrict__ Uh_bf,
    const float* __restrict__ hv_g, const float* __restrict__ hv2_g,
    const float* __restrict__ Tk_w, const float* __restrict__ vk_w,
    const float* __restrict__ vk_b, const float* __restrict__ Wt_w,
    const float* __restrict__ Vt_b, const float* __restrict__ WHd,
    const float* __restrict__ WTd, const uint32* __restrict__ cellw,
    const float* __restrict__ RHb, const float* __restrict__ RTb,
    const float* __restrict__ W_w, const float* __restrict__ W_b,
    const float* __restrict__ V_b, float* __restrict__ out) {
  const int b = blockIdx.x, tid = threadIdx.x;

  __shared__ uint32 tk_lds[24576];  // 96 KiB packed bf16 n-pairs, swizzled
  __shared__ __align__(8) float Ts_lds[3 * 136];  // padded 34-float windows
  __shared__ __align__(8) float vk_pad[3 * 136];
  __shared__ __align__(8) float a_lds[768];
  __shared__ __align__(8) float hv_lds[768];
  __shared__ __align__(8) float hv2_lds[768];
  __shared__ __align__(8) float s_lds[128];
  __shared__ float cpart[8 * 128];
  __shared__ float bias_lds[1024];  // RHb[384] RTb[384] WHd[128] WTd[128]
  __shared__ float y_lds[256];
  __shared__ float redN[12], redD[12], redN2[12];
  __shared__ float ytil_lds;

  // ---- one-time LDS fills ----
  for (int i = tid; i < 24576; i += 1024) {
    int r = i >> 13, rem = i & 8191, j = rem >> 7, m = rem & 127;
    float g0 = Tk_w[(size_t)r * 16384 + (2 * j) * 128 + m];
    float g1 = Tk_w[(size_t)r * 16384 + (2 * j + 1) * 128 + m];
    tk_lds[r * 8192 + m * 64 + (j ^ (m & 31))] =
        (uint32)f2bf(g0) | ((uint32)f2bf(g1) << 16);
  }
  if (tid < 384) {
    int r = tid >> 7, m = tid & 127;
    vk_pad[r * 136 + (m >> 5) * 34 + (m & 31)] = vk_w[tid];
    bias_lds[tid] = RHb[tid];
    bias_lds[384 + tid] = RTb[tid];
  }
  if (tid < 128) {
    bias_lds[768 + tid] = WHd[tid];
    bias_lds[896 + tid] = WTd[tid];
    s_lds[tid] = 0.f;
  }
  if (tid < 256) y_lds[tid] = y[(b << 8) + tid];
  if (tid < 768) {
    hv_lds[tid] = hv_g[(size_t)b * 768 + tid];
    hv2_lds[tid] = hv2_g[(size_t)b * 768 + tid];
  }
  const float wt0 = Wt_w[0], vtb0 = Vt_b[0];
  float vkb[3] = {vk_b[0], vk_b[1], vk_b[2]};

  // ---- persistent Uh registers: thread (t_e4, q4) holds m in [q4*32, +32) ----
  const int t_e4 = tid >> 2, q4 = tid & 3;
  uint32 ureg[3][16];
#pragma unroll
  for (int r = 0; r < 3; ++r) {
    const uint4* up = (const uint4*)(Uh_bf +
        ((size_t)(b * 3 + r) * 256 + t_e4) * 128 + q4 * 32);
#pragma unroll
    for (int q = 0; q < 4; ++q) {
      uint4 v = up[q];
      ureg[r][4 * q + 0] = v.x;
      ureg[r][4 * q + 1] = v.y;
      ureg[r][4 * q + 2] = v.z;
      ureg[r][4 * q + 3] = v.w;
    }
  }
  // Anti-remat: xor with an opaque zero (multi-instr chains aren't remat-able).
  uint32 zr;
  asm volatile("s_mov_b32 %0, 0" : "=s"(zr));
#pragma unroll
  for (int r = 0; r < 3; ++r)
#pragma unroll
    for (int q = 0; q < 16; ++q) ureg[r][q] ^= zr;
  __syncthreads();

  const int lane = tid & 63, wv = tid >> 6;
  // Ts-phase roles (tid < 768)
  const int r3t = (tid >> 8) & 3, m2 = (tid >> 1) & 127, p2 = tid & 1;
  // cell roles: 2 gates x 4 n2-chunks x 128 m
  const int gc = tid >> 9, ch = (tid >> 7) & 3, mc = tid & 127;
  const uint32* Wc = cellw + gc * 24576 + mc;
  const int n2base = ch * 16;

  for (int step = 0; step < 256; ++step) {
    // ---- Ts[r][m] = s @ Tk[r] ----
    if (tid < 768) {
      const uint32* tkp = tk_lds + r3t * 8192 + m2 * 64;
      const int swz = m2 & 31;
      const float* sp = s_lds + p2 * 64;
      const int jb = p2 * 32;
      float acc = 0.f;
#pragma unroll 8
      for (int jj = 0; jj < 32; ++jj) {
        uint32 w = tkp[(jb + jj) ^ swz];
        float2 sv = *(const float2*)(sp + 2 * jj);
        acc += sv.x * bf2f_lo(w) + sv.y * bf2f_hi(w);
      }
      float tot = acc + __shfl_xor(acc, 1);
      if (p2 == 0) Ts_lds[r3t * 136 + (m2 >> 5) * 34 + (m2 & 31)] = tot;
    }
    __syncthreads();  // (1)
    // ---- e[r][t'] = vk . tanh(Uh + Ts) + vkb (Uh in registers) ----
    {
      float er[3];
#pragma unroll
      for (int r = 0; r < 3; ++r) {
        const float2* ts2 = (const float2*)(Ts_lds + r * 136 + q4 * 34);
        const float2* vk2 = (const float2*)(vk_pad + r * 136 + q4 * 34);
        float acc = 0.f;
#pragma unroll
        for (int j = 0; j < 16; ++j) {
          uint32 w = ureg[r][j];
          float2 t2 = ts2[j], v2 = vk2[j];
          acc += v2.x * tanh_fast(bf2f_lo(w) + t2.x);
          acc += v2.y * tanh_fast(bf2f_hi(w) + t2.y);
        }
        acc += __shfl_xor(acc, 1);
        acc += __shfl_xor(acc, 2);
        er[r] = acc;
      }
      if (q4 == 0) {
#pragma unroll
        for (int r = 0; r < 3; ++r) a_lds[r * 256 + t_e4] = er[r] + vkb[r];
      }
    }
    __syncthreads();  // (2)
    // ---- p = exp(e); num/den partial sums per r (no max-sub needed) ----
    {
      float pn = 0.f, pd = 0.f, pn2 = 0.f;
      if (tid < 768) {
        float p = __expf(a_lds[tid]);
        pd = p;
        pn = p * hv_lds[tid];
        if (step == 255) pn2 = p * hv2_lds[tid];
      }
#pragma unroll
      for (int off = 32; off; off >>= 1) {
        pn += __shfl_xor(pn, off);
        pd += __shfl_xor(pd, off);
      }
      if (step == 255) {
#pragma unroll
        for (int off = 32; off; off >>= 1) pn2 += __shfl_xor(pn2, off);
      }
      if (lane == 0 && wv < 12) {
        redN[wv] = pn;
        redD[wv] = pd;
        if (step == 255) redN2[wv] = pn2;
      }
    }
    __syncthreads();  // (3)
    // ---- cell: 3 micro-steps; l=0 partial overlaps ytil scalar ----
    const float2* sp2 = (const float2*)s_lds;
#pragma unroll
    for (int l = 0; l < 3; ++l) {
      {
        float acc = 0.f;
        const uint32* wp = Wc + (size_t)(l * 64 + n2base) * 128;
#pragma unroll 8
        for (int n2 = 0; n2 < 16; ++n2) {
          uint32 w = wp[(size_t)n2 * 128];
          float2 sv = sp2[n2base + n2];
          acc += sv.x * bf2f_lo(w) + sv.y * bf2f_hi(w);
        }
        cpart[(gc * 4 + ch) * 128 + mc] = acc;
        if (l == 0 && tid == 0) {
          float yt = y_lds[step] * wt0 + vtb0;
#pragma unroll
          for (int r = 0; r < 3; ++r) {
            float ns = redN[4 * r] + redN[4 * r + 1] + redN[4 * r + 2] + redN[4 * r + 3];
            float ds = redD[4 * r] + redD[4 * r + 1] + redD[4 * r + 2] + redD[4 * r + 3];
            yt += ns * rcp_fast(ds);
          }
          ytil_lds = yt;
        }
      }
      __syncthreads();  // cell A
      if (tid < 128) {
        float ha = cpart[tid] + cpart[128 + tid] + cpart[256 + tid] +
                   cpart[384 + tid] + bias_lds[l * 128 + tid];
        float ta = cpart[512 + tid] + cpart[640 + tid] + cpart[768 + tid] +
                   cpart[896 + tid] + bias_lds[384 + l * 128 + tid];
        if (l == 0) {
          float yt = ytil_lds;
          ha += yt * bias_lds[768 + tid];
          ta += yt * bias_lds[896 + tid];
        }
        float hvv = tanh_fast(ha);
        float tv = sigmoid_fast(ta);
        s_lds[tid] = hvv * tv + (1.f - tv) * s_lds[tid];
      }
      __syncthreads();  // cell B
    }
  }
  // ---- output head: out[b] = s.W_w + W_b + V_b + sum_r num2[r]/den[r] ----
  if (tid < 64) {
    float acc = s_lds[tid] * W_w[tid] + s_lds[tid + 64] * W_w[tid + 64];
#pragma unroll
    for (int off = 32; off; off >>= 1) acc += __shfl_xor(acc, off);
    if (tid == 0) {
      float o = acc + W_b[0] + V_b[0];
#pragma unroll
      for (int r = 0; r < 3; ++r) {
        float ns = redN2[4 * r] + redN2[4 * r + 1] + redN2[4 * r + 2] + redN2[4 * r + 3];
        float ds = redD[4 * r] + redD[4 * r + 1] + redD[4 * r + 2] + redD[4 * r + 3];
        o += ns * rcp_fast(ds);
      }
      out[b] = o;
    }
  }
}

extern "C" void kernel_launch(void* const* d_in, const int* in_sizes, int n_in,
                              void* d_out, int out_size, void* d_ws,
                              size_t ws_size, hipStream_t stream) {
  (void)in_sizes; (void)n_in; (void)out_size; (void)ws_size;
  const float* x    = (const float*)d_in[0];
  const float* y    = (const float*)d_in[1];
  const float* c0w  = (const float*)d_in[2];
  const float* c0b  = (const float*)d_in[3];
  const float* c1w  = (const float*)d_in[4];
  const float* c1b  = (const float*)d_in[5];
  const float* c2ew = (const float*)d_in[6];
  const float* c2eb = (const float*)d_in[7];
  const float* eWH  = (const float*)d_in[8];
  const float* eWT  = (const float*)d_in[9];
  const float* eRHw = (const float*)d_in[10];
  const float* eRHb = (const float*)d_in[11];
  const float* eRTw = (const float*)d_in[12];
  const float* eRTb = (const float*)d_in[13];
  const float* dWH  = (const float*)d_in[14];
  const float* dWT  = (const float*)d_in[15];
  const float* dRHw = (const float*)d_in[16];
  const float* dRHb = (const float*)d_in[17];
  const float* dRTw = (const float*)d_in[18];
  const float* dRTb = (const float*)d_in[19];
  const float* Tk   = (const float*)d_in[20];
  const float* Ukw  = (const float*)d_in[21];
  const float* Ukb  = (const float*)d_in[22];
  const float* vkw  = (const float*)d_in[23];
  const float* vkb  = (const float*)d_in[24];
  const float* Wtw  = (const float*)d_in[25];
  const float* Vtw  = (const float*)d_in[26];
  const float* Vtb  = (const float*)d_in[27];
  const float* Ww   = (const float*)d_in[28];
  const float* Wb   = (const float*)d_in[29];
  const float* Vw   = (const float*)d_in[30];
  const float* Vb   = (const float*)d_in[31];
  float* out = (float*)d_out;
  float* ws = (float*)d_ws;

  // Workspace layout (float units). Total 151.2 MB + 196 KB (unchanged).
  // h_bf  [0, 12582912) bf16; Uh_bf [12582912, 25165824) bf16 (aliases xph).
  // xph [12582912, 20971520); xpt [20971520, 29360128) — dead after encoder.
  // hv/hv2 in old c0o region [29360128, +1572864) — dead after conv1.
  // c1o [33554432, 37748736); cellw [37748736, +49152).
  unsigned short* h_bf  = (unsigned short*)ws;
  unsigned short* Uh_bf = (unsigned short*)(ws + 12582912);
  float* xph = ws + 12582912;
  float* xpt = ws + 20971520;
  float* c0o = ws + 29360128;
  float* hv  = ws + 29360128;   // aliases c0o (dead by k_hv time)
  float* hv2 = ws + 30146560;
  float* c1o = ws + 33554432;
  uint32* cellw = (uint32*)(ws + 37748736);

  k_prep<<<192, 256, 0, stream>>>(dRHw, dRTw, cellw);
  k_conv0<<<1024, 256, 0, stream>>>(x, c0w, c0b, c0o);
  k_conv1<<<1024, 256, 0, stream>>>(c0o, c1w, c1b, c1o);
  k_c2e_proj<<<1024, 256, 0, stream>>>(c1o, c2ew, c2eb, eWH, eWT, xph, xpt);
  k_encoder<<<256, 512, 0, stream>>>(xph, xpt, eRHw, eRHb, eRTw, eRTb, h_bf);
  k_uh<<<6144, 256, 0, stream>>>(h_bf, Ukw, Ukb, Uh_bf);
  k_hv<<<256, 768, 0, stream>>>(h_bf, Vtw, Vw, hv, hv2);
  k_decoder<<<256, 1024, 0, stream>>>(y, Uh_bf, hv, hv2, Tk, vkw, vkb, Wtw,
                                      Vtb, dWH, dWT, cellw, dRHb, dRTb,
                                      Ww, Wb, Vb, out);
}